// Round 2
// baseline (275.822 us; speedup 1.0000x reference)
//
#include <hip/hip_runtime.h>
#include <hip/hip_bf16.h>
#include <math.h>

// Problem constants
#define B_SZ   64
#define N_SZ   1024
#define M_SZ   4096
#define HID_SZ 2048
#define OUT_SZ 512

// ---------------------------------------------------------------------------
// Kernel 1: pairwise min-distance.
//   x[b][n] = min_j || pos[b,n,:] - basis[j,:] ||
// Rewritten: d2 = p2 + 2 * min_j ( 0.5*|q_j|^2 - p.q_j );  sqrt after min.
// Each block: 128 points, ALL 4096 basis held in registers (16/lane * 64
// lanes * 4 waves). Inner loop: 3 FMA per pair (basis comps in VGPRs, point
// comps uniform -> SGPR), 3-way-grouped min tree (v_min3_f32).
// NOTE: point loop is FULLY unrolled — partial unroll would runtime-index
// pc[] and spill it to scratch (rule #20).
// Output written transposed: xT[n][b]  (layer-0 GEMM consumes it that way).
// ---------------------------------------------------------------------------
__global__ __launch_bounds__(256) void dist_min_kernel(
    const float* __restrict__ pos,    // [B*N][3] = [65536][3]
    const float* __restrict__ basis,  // [M][3]
    float* __restrict__ xT)           // [N][B] = [1024][64]
{
  const int tid  = threadIdx.x;
  const int lane = tid & 63;
  const int wave = tid >> 6;

  // Load 16 basis vectors per lane (whole block covers all M=4096),
  // pre-negated, with c = 0.5*|q|^2 folded in.
  float nqx[16], nqy[16], nqz[16], qc[16];
#pragma unroll
  for (int i = 0; i < 16; ++i) {
    int j = wave * 1024 + i * 64 + lane;
    float qx = basis[3*j+0], qy = basis[3*j+1], qz = basis[3*j+2];
    nqx[i] = -qx; nqy[i] = -qy; nqz[i] = -qz;
    qc[i]  = 0.5f * (qx*qx + qy*qy + qz*qz);
  }

  __shared__ float red[16][256];   // 16 KiB: per-(point,thread) partial mins

  const int pbase = blockIdx.x * 128;

  for (int c = 0; c < 8; ++c) {            // 8 chunks of 16 points
    const int cbase = pbase + c * 16;

    // Preload the 16 points' coords. Uniform address -> scalar loads (SGPR).
    const float* pp = pos + (size_t)3 * cbase;
    float pc[48];
#pragma unroll
    for (int e = 0; e < 48; ++e) pc[e] = pp[e];

#pragma unroll   // FULL unroll: all pc[]/t[] indices must be compile-time
    for (int p = 0; p < 16; ++p) {
      const float px = pc[3*p+0], py = pc[3*p+1], pz = pc[3*p+2];
      float t[16];
#pragma unroll
      for (int i = 0; i < 16; ++i) t[i] = fmaf(nqx[i], px, qc[i]);
#pragma unroll
      for (int i = 0; i < 16; ++i) t[i] = fmaf(nqy[i], py, t[i]);
#pragma unroll
      for (int i = 0; i < 16; ++i) t[i] = fmaf(nqz[i], pz, t[i]);
      // 3-way-grouped min tree -> v_min3_f32 fusion (7 min3 + 1 min)
      float m0 = fminf(fminf(t[0],  t[1]),  t[2]);
      float m1 = fminf(fminf(t[3],  t[4]),  t[5]);
      float m2 = fminf(fminf(t[6],  t[7]),  t[8]);
      float m3 = fminf(fminf(t[9],  t[10]), t[11]);
      float m4 = fminf(fminf(t[12], t[13]), t[14]);
      float r0 = fminf(fminf(m0, m1), m2);
      float r1 = fminf(fminf(m3, m4), t[15]);
      red[p][tid] = fminf(r0, r1);
    }
    __syncthreads();

    // Phase 2: reduce 256 partials per point; 16 threads/point.
    {
      const int p   = tid >> 4;
      const int sub = tid & 15;
      const float4* r4 = (const float4*)&red[p][sub * 16];
      float4 v0 = r4[0], v1 = r4[1], v2 = r4[2], v3 = r4[3];
      float w0 = fminf(fminf(v0.x, v0.y), fminf(v0.z, v0.w));
      float w1 = fminf(fminf(v1.x, v1.y), fminf(v1.z, v1.w));
      float w2 = fminf(fminf(v2.x, v2.y), fminf(v2.z, v2.w));
      float w3 = fminf(fminf(v3.x, v3.y), fminf(v3.z, v3.w));
      float v  = fminf(fminf(w0, w1), fminf(w2, w3));
#pragma unroll
      for (int o = 1; o < 16; o <<= 1) v = fminf(v, __shfl_xor(v, o));
      if (sub == 0) {
        int i = cbase + p;
        float px = pos[3*i+0], py = pos[3*i+1], pz = pos[3*i+2];
        float p2 = px*px + py*py + pz*pz;
        float d2 = fmaf(2.f, v, p2);
        d2 = fmaxf(d2, 1e-12f);
        int n = i & (N_SZ - 1);
        int b = i >> 10;
        xT[n * 64 + b] = sqrtf(d2);
      }
    }
    __syncthreads();
  }
}

// ---------------------------------------------------------------------------
// Kernel 2: K-split partial GEMM (fp32 vector; no fp32 MFMA on CDNA4).
//   P[s][j][b] = sum_{k in chunk s} xT[k][b] * W[k][j]
// Block = 512 threads (8 waves) covering a 128(j) x 64(b) output tile for one
// K-chunk. Lane holds a 4x4 (b x j) accumulator: 16 FMA per (dwordx4 W +
// dwordx4 x) load pair. W loads coalesced along j; x chunk (<=32KB) L1-hot.
// grid = (J/128, K/KC).
// ---------------------------------------------------------------------------
template <int J, int KC>
__global__ __launch_bounds__(512) void gemm_part(
    const float* __restrict__ xT,   // [K][64]
    const float* __restrict__ W,    // [K][J]
    float* __restrict__ P)          // [ks][J][64]
{
  const int jt   = blockIdx.x;
  const int s    = blockIdx.y;
  const int lane = threadIdx.x & 63;
  const int wave = threadIdx.x >> 6;
  const int j0 = jt * 128 + (lane & 31) * 4;
  const int b0 = wave * 8 + (lane >> 5) * 4;

  const float* wp = W  + (size_t)s * KC * J  + j0;
  const float* xp = xT + (size_t)s * KC * 64 + b0;

  float acc[4][4];
#pragma unroll
  for (int a = 0; a < 4; ++a)
#pragma unroll
    for (int c = 0; c < 4; ++c) acc[a][c] = 0.f;

#pragma unroll 8
  for (int k = 0; k < KC; ++k) {
    float4 w4 = *(const float4*)(wp + (size_t)k * J);
    float4 x4 = *(const float4*)(xp + k * 64);
    const float wv[4] = {w4.x, w4.y, w4.z, w4.w};
    const float xv[4] = {x4.x, x4.y, x4.z, x4.w};
#pragma unroll
    for (int a = 0; a < 4; ++a)
#pragma unroll
      for (int c = 0; c < 4; ++c)
        acc[a][c] = fmaf(xv[a], wv[c], acc[a][c]);
  }

#pragma unroll
  for (int c = 0; c < 4; ++c) {
    float4 o = make_float4(acc[0][c], acc[1][c], acc[2][c], acc[3][c]);
    *(float4*)(P + ((size_t)s * J + (j0 + c)) * 64 + b0) = o;
  }
}

// ---------------------------------------------------------------------------
// Kernel 3: reduce K-split partials + bias (+ReLU), write activation
// transposed xT[j][b] for the next layer (or final out[b][j] row-major).
// Thread t -> (j = t>>6, b = t&63): coalesced partial reads.
// ---------------------------------------------------------------------------
template <int J, int KS, bool RELU, bool TRANS>
__global__ __launch_bounds__(256) void reduce_bias_kernel(
    const float* __restrict__ P,     // [KS][J][64]
    const float* __restrict__ bias,  // [J]
    float* __restrict__ out)         // TRANS ? [J][64] : [B][J]
{
  const int t = blockIdx.x * 256 + threadIdx.x;
  const int b = t & 63;
  const int j = t >> 6;
  float v = 0.f;
#pragma unroll
  for (int s = 0; s < KS; ++s) v += P[((size_t)s * J + j) * 64 + b];
  v += bias[j];
  if (RELU) v = fmaxf(v, 0.f);
  if (TRANS) out[j * 64 + b] = v;
  else       out[(size_t)b * J + j] = v;
}

// ---------------------------------------------------------------------------
extern "C" void kernel_launch(void* const* d_in, const int* in_sizes, int n_in,
                              void* d_out, int out_size, void* d_ws, size_t ws_size,
                              hipStream_t stream) {
  const float* pos   = (const float*)d_in[0];
  const float* basis = (const float*)d_in[1];
  const float* W0    = (const float*)d_in[2];
  const float* b0    = (const float*)d_in[3];
  const float* W1    = (const float*)d_in[4];
  const float* b1    = (const float*)d_in[5];
  const float* W2    = (const float*)d_in[6];
  const float* b2    = (const float*)d_in[7];
  const float* W3    = (const float*)d_in[8];
  const float* b3    = (const float*)d_in[9];
  float* out = (float*)d_out;

  char* ws = (char*)d_ws;
  float* P  = (float*)ws;                                  // 8 MiB partials
  float* xA = (float*)(ws + (8u << 20));                   // 512 KiB
  float* xB = (float*)(ws + (8u << 20) + (512u << 10));    // 512 KiB

  // 1) distances + min -> xT0 [1024][64] in xA
  dist_min_kernel<<<512, 256, 0, stream>>>(pos, basis, xA);

  // 2) layer 0: [64,1024] @ [1024,2048], ks=16 (KC=64)
  gemm_part<HID_SZ, 64><<<dim3(HID_SZ / 128, 16), 512, 0, stream>>>(xA, W0, P);
  reduce_bias_kernel<HID_SZ, 16, true, true>
      <<<HID_SZ * 64 / 256, 256, 0, stream>>>(P, b0, xB);

  // 3) layer 1: [64,2048] @ [2048,2048], ks=16 (KC=128)
  gemm_part<HID_SZ, 128><<<dim3(HID_SZ / 128, 16), 512, 0, stream>>>(xB, W1, P);
  reduce_bias_kernel<HID_SZ, 16, true, true>
      <<<HID_SZ * 64 / 256, 256, 0, stream>>>(P, b1, xA);

  // 4) layer 2
  gemm_part<HID_SZ, 128><<<dim3(HID_SZ / 128, 16), 512, 0, stream>>>(xA, W2, P);
  reduce_bias_kernel<HID_SZ, 16, true, true>
      <<<HID_SZ * 64 / 256, 256, 0, stream>>>(P, b2, xB);

  // 5) layer 3: [64,2048] @ [2048,512], ks=64 (KC=32); final out row-major
  gemm_part<OUT_SZ, 32><<<dim3(OUT_SZ / 128, 64), 512, 0, stream>>>(xB, W3, P);
  reduce_bias_kernel<OUT_SZ, 64, false, false>
      <<<OUT_SZ * 64 / 256, 256, 0, stream>>>(P, b3, out);
}

// Round 3
// 201.023 us; speedup vs baseline: 1.3721x; 1.3721x over previous
//
#include <hip/hip_runtime.h>
#include <hip/hip_bf16.h>
#include <math.h>

// Problem constants
#define B_SZ   64
#define N_SZ   1024
#define M_SZ   4096
#define HID_SZ 2048
#define OUT_SZ 512

// ---------------------------------------------------------------------------
// Kernel 1: pairwise min-distance (unchanged from r1; VALU-bound by design).
//   xT[n][b] = min_j || pos[b,n,:] - basis[j,:] ||
// ---------------------------------------------------------------------------
__global__ __launch_bounds__(256) void dist_min_kernel(
    const float* __restrict__ pos,    // [B*N][3] = [65536][3]
    const float* __restrict__ basis,  // [M][3]
    float* __restrict__ xT)           // [N][B] = [1024][64]
{
  const int tid  = threadIdx.x;
  const int lane = tid & 63;
  const int wave = tid >> 6;

  float nqx[16], nqy[16], nqz[16], qc[16];
#pragma unroll
  for (int i = 0; i < 16; ++i) {
    int j = wave * 1024 + i * 64 + lane;
    float qx = basis[3*j+0], qy = basis[3*j+1], qz = basis[3*j+2];
    nqx[i] = -qx; nqy[i] = -qy; nqz[i] = -qz;
    qc[i]  = 0.5f * (qx*qx + qy*qy + qz*qz);
  }

  __shared__ float red[16][256];

  const int pbase = blockIdx.x * 128;

  for (int c = 0; c < 8; ++c) {
    const int cbase = pbase + c * 16;
    const float* pp = pos + (size_t)3 * cbase;
    float pc[48];
#pragma unroll
    for (int e = 0; e < 48; ++e) pc[e] = pp[e];

#pragma unroll   // FULL unroll: keep pc[]/t[] indices compile-time (rule #20)
    for (int p = 0; p < 16; ++p) {
      const float px = pc[3*p+0], py = pc[3*p+1], pz = pc[3*p+2];
      float t[16];
#pragma unroll
      for (int i = 0; i < 16; ++i) t[i] = fmaf(nqx[i], px, qc[i]);
#pragma unroll
      for (int i = 0; i < 16; ++i) t[i] = fmaf(nqy[i], py, t[i]);
#pragma unroll
      for (int i = 0; i < 16; ++i) t[i] = fmaf(nqz[i], pz, t[i]);
      float m0 = fminf(fminf(t[0],  t[1]),  t[2]);
      float m1 = fminf(fminf(t[3],  t[4]),  t[5]);
      float m2 = fminf(fminf(t[6],  t[7]),  t[8]);
      float m3 = fminf(fminf(t[9],  t[10]), t[11]);
      float m4 = fminf(fminf(t[12], t[13]), t[14]);
      float r0 = fminf(fminf(m0, m1), m2);
      float r1 = fminf(fminf(m3, m4), t[15]);
      red[p][tid] = fminf(r0, r1);
    }
    __syncthreads();

    {
      const int p   = tid >> 4;
      const int sub = tid & 15;
      const float4* r4 = (const float4*)&red[p][sub * 16];
      float4 v0 = r4[0], v1 = r4[1], v2 = r4[2], v3 = r4[3];
      float w0 = fminf(fminf(v0.x, v0.y), fminf(v0.z, v0.w));
      float w1 = fminf(fminf(v1.x, v1.y), fminf(v1.z, v1.w));
      float w2 = fminf(fminf(v2.x, v2.y), fminf(v2.z, v2.w));
      float w3 = fminf(fminf(v3.x, v3.y), fminf(v3.z, v3.w));
      float v  = fminf(fminf(w0, w1), fminf(w2, w3));
#pragma unroll
      for (int o = 1; o < 16; o <<= 1) v = fminf(v, __shfl_xor(v, o));
      if (sub == 0) {
        int i = cbase + p;
        float px = pos[3*i+0], py = pos[3*i+1], pz = pos[3*i+2];
        float p2 = px*px + py*py + pz*pz;
        float d2 = fmaf(2.f, v, p2);
        d2 = fmaxf(d2, 1e-12f);
        int n = i & (N_SZ - 1);
        int b = i >> 10;
        xT[n * 64 + b] = sqrtf(d2);
      }
    }
    __syncthreads();
  }
}

// ---------------------------------------------------------------------------
// Kernel 2 (v2): K-split partial GEMM, explicitly software-pipelined.
//   P[s][j][b] = sum_{k in block's KSPAN chunk} xT[k][b] * W[k][j]
// Block = 256 thr (4 waves), output tile 64(j) x 64(b); x chunk staged in LDS.
// Wave layout: jl = lane&15 -> 4 j's each (16 lanes x 16B = 256B contiguous W
// load, other 3 lane-quads duplicate-collapse); b0 = wave*16 + (lane>>4)*4.
// Inner loop: double-buffered batches of 8 k-steps, all register arrays
// indexed by compile-time constants (rule #20). Per wave, 8x256B W loads in
// flight -> 16KB/CU outstanding at 8 waves/CU >= Little's-law (~9.2KB).
// ---------------------------------------------------------------------------
template <int J, int KSPAN>
__global__ __launch_bounds__(256) void gemm2_kernel(
    const float* __restrict__ xT,   // [K][64]
    const float* __restrict__ W,    // [K][J]
    float* __restrict__ P)          // [ks][J][64]
{
  const int jt   = blockIdx.x;
  const int s    = blockIdx.y;
  const int tid  = threadIdx.x;
  const int lane = tid & 63;
  const int wave = tid >> 6;
  const int jl = lane & 15;
  const int bq = lane >> 4;
  const int j0 = jt * 64 + jl * 4;
  const int b0 = wave * 16 + bq * 4;

  __shared__ float xs[KSPAN][64];
  {
    const float4* src4 = (const float4*)(xT + (size_t)s * KSPAN * 64);
    float4* dst4 = (float4*)&xs[0][0];
    constexpr int NITER = (KSPAN * 16) / 256;
#pragma unroll
    for (int i = 0; i < NITER; ++i)
      dst4[i * 256 + tid] = src4[i * 256 + tid];
  }
  __syncthreads();

  const float* wp = W + (size_t)s * KSPAN * J + j0;

  float acc[4][4];
#pragma unroll
  for (int a = 0; a < 4; ++a)
#pragma unroll
    for (int c = 0; c < 4; ++c) acc[a][c] = 0.f;

  float4 wa[8], xa[8], wb[8], xb[8];

  // prologue: batch A <- k = 0..7
#pragma unroll
  for (int u = 0; u < 8; ++u) {
    wa[u] = *(const float4*)(wp + (size_t)u * J);
    xa[u] = *(const float4*)&xs[u][b0];
  }

#pragma unroll 1
  for (int kk = 0; kk < KSPAN; kk += 16) {
    // issue batch B <- k = kk+8 .. kk+15 (always in range)
#pragma unroll
    for (int u = 0; u < 8; ++u) {
      wb[u] = *(const float4*)(wp + (size_t)(kk + 8 + u) * J);
      xb[u] = *(const float4*)&xs[kk + 8 + u][b0];
    }
    // compute batch A (k = kk .. kk+7)
#pragma unroll
    for (int u = 0; u < 8; ++u) {
      const float xv[4] = {xa[u].x, xa[u].y, xa[u].z, xa[u].w};
      const float wv[4] = {wa[u].x, wa[u].y, wa[u].z, wa[u].w};
#pragma unroll
      for (int a = 0; a < 4; ++a)
#pragma unroll
        for (int c = 0; c < 4; ++c)
          acc[a][c] = fmaf(xv[a], wv[c], acc[a][c]);
    }
    // issue next batch A <- k = kk+16 .. kk+23 (guarded, uniform branch)
    if (kk + 16 < KSPAN) {
#pragma unroll
      for (int u = 0; u < 8; ++u) {
        wa[u] = *(const float4*)(wp + (size_t)(kk + 16 + u) * J);
        xa[u] = *(const float4*)&xs[kk + 16 + u][b0];
      }
    }
    // compute batch B
#pragma unroll
    for (int u = 0; u < 8; ++u) {
      const float xv[4] = {xb[u].x, xb[u].y, xb[u].z, xb[u].w};
      const float wv[4] = {wb[u].x, wb[u].y, wb[u].z, wb[u].w};
#pragma unroll
      for (int a = 0; a < 4; ++a)
#pragma unroll
        for (int c = 0; c < 4; ++c)
          acc[a][c] = fmaf(xv[a], wv[c], acc[a][c]);
    }
  }

#pragma unroll
  for (int c = 0; c < 4; ++c) {
    float4 o = make_float4(acc[0][c], acc[1][c], acc[2][c], acc[3][c]);
    *(float4*)(P + ((size_t)s * J + (j0 + c)) * 64 + b0) = o;
  }
}

// ---------------------------------------------------------------------------
// Kernel 3: reduce K-split partials + bias (+ReLU); optional transposed write.
// ---------------------------------------------------------------------------
template <int J, int KS, bool RELU, bool TRANS>
__global__ __launch_bounds__(256) void reduce_bias_kernel(
    const float* __restrict__ P,     // [KS][J][64]
    const float* __restrict__ bias,  // [J]
    float* __restrict__ out)         // TRANS ? [J][64] : [B][J]
{
  const int t = blockIdx.x * 256 + threadIdx.x;
  const int b = t & 63;
  const int j = t >> 6;
  float v = 0.f;
#pragma unroll
  for (int s = 0; s < KS; ++s) v += P[((size_t)s * J + j) * 64 + b];
  v += bias[j];
  if (RELU) v = fmaxf(v, 0.f);
  if (TRANS) out[j * 64 + b] = v;
  else       out[(size_t)b * J + j] = v;
}

// ---------------------------------------------------------------------------
extern "C" void kernel_launch(void* const* d_in, const int* in_sizes, int n_in,
                              void* d_out, int out_size, void* d_ws, size_t ws_size,
                              hipStream_t stream) {
  const float* pos   = (const float*)d_in[0];
  const float* basis = (const float*)d_in[1];
  const float* W0    = (const float*)d_in[2];
  const float* b0    = (const float*)d_in[3];
  const float* W1    = (const float*)d_in[4];
  const float* b1    = (const float*)d_in[5];
  const float* W2    = (const float*)d_in[6];
  const float* b2    = (const float*)d_in[7];
  const float* W3    = (const float*)d_in[8];
  const float* b3    = (const float*)d_in[9];
  float* out = (float*)d_out;

  char* ws = (char*)d_ws;
  float* P  = (float*)ws;                                  // 8 MiB partials
  float* xA = (float*)(ws + (8u << 20));                   // 512 KiB
  float* xB = (float*)(ws + (8u << 20) + (512u << 10));    // 512 KiB

  // 1) distances + min -> xT0 [1024][64] in xA
  dist_min_kernel<<<512, 256, 0, stream>>>(pos, basis, xA);

  // 2) layer 0: [64,1024] @ [1024,2048]; KSPAN=64 -> 16 slices, 512 blocks
  gemm2_kernel<HID_SZ, 64>
      <<<dim3(HID_SZ / 64, 1024 / 64), 256, 0, stream>>>(xA, W0, P);
  reduce_bias_kernel<HID_SZ, 16, true, true>
      <<<HID_SZ * 64 / 256, 256, 0, stream>>>(P, b0, xB);

  // 3) layer 1: [64,2048] @ [2048,2048]; KSPAN=128 -> 16 slices, 512 blocks
  gemm2_kernel<HID_SZ, 128>
      <<<dim3(HID_SZ / 64, 2048 / 128), 256, 0, stream>>>(xB, W1, P);
  reduce_bias_kernel<HID_SZ, 16, true, true>
      <<<HID_SZ * 64 / 256, 256, 0, stream>>>(P, b1, xA);

  // 4) layer 2
  gemm2_kernel<HID_SZ, 128>
      <<<dim3(HID_SZ / 64, 2048 / 128), 256, 0, stream>>>(xA, W2, P);
  reduce_bias_kernel<HID_SZ, 16, true, true>
      <<<HID_SZ * 64 / 256, 256, 0, stream>>>(P, b2, xB);

  // 5) layer 3: [64,2048] @ [2048,512]; KSPAN=32 -> 64 slices, 512 blocks
  gemm2_kernel<OUT_SZ, 32>
      <<<dim3(OUT_SZ / 64, 2048 / 32), 256, 0, stream>>>(xB, W3, P);
  reduce_bias_kernel<OUT_SZ, 64, false, false>
      <<<OUT_SZ * 64 / 256, 256, 0, stream>>>(P, b3, out);
}

// Round 5
// 199.316 us; speedup vs baseline: 1.3838x; 1.0086x over previous
//
#include <hip/hip_runtime.h>
#include <hip/hip_bf16.h>
#include <math.h>

// Problem constants
#define B_SZ   64
#define N_SZ   1024
#define M_SZ   4096
#define HID_SZ 2048
#define OUT_SZ 512

#define AS1 __attribute__((address_space(1)))
#define AS3 __attribute__((address_space(3)))

// ---------------------------------------------------------------------------
// Kernel 1: pairwise min-distance.
//   xT[n][b] = min_j || pos[b,n,:] - basis[j,:] ||
// d2 = p2 + 2*min_j(0.5*|q|^2 - p.q); sqrt after min. All 4096 basis in
// registers (16/lane). launch_bounds(256,2): VGPR cap 256 so the 64-reg
// basis bank + fully-unrolled point loop cannot spill.
// ---------------------------------------------------------------------------
__global__ __launch_bounds__(256, 2) void dist_min_kernel(
    const float* __restrict__ pos,    // [B*N][3] = [65536][3]
    const float* __restrict__ basis,  // [M][3]
    float* __restrict__ xT)           // [N][B] = [1024][64]
{
  const int tid  = threadIdx.x;
  const int lane = tid & 63;
  const int wave = tid >> 6;

  float nqx[16], nqy[16], nqz[16], qc[16];
#pragma unroll
  for (int i = 0; i < 16; ++i) {
    int j = wave * 1024 + i * 64 + lane;
    float qx = basis[3*j+0], qy = basis[3*j+1], qz = basis[3*j+2];
    nqx[i] = -qx; nqy[i] = -qy; nqz[i] = -qz;
    qc[i]  = 0.5f * (qx*qx + qy*qy + qz*qz);
  }

  __shared__ float red[16][256];

  const int pbase = blockIdx.x * 128;

  for (int c = 0; c < 8; ++c) {
    const int cbase = pbase + c * 16;
    const float* pp = pos + (size_t)3 * cbase;
    float pc[48];
#pragma unroll
    for (int e = 0; e < 48; ++e) pc[e] = pp[e];

#pragma unroll   // FULL unroll: keep pc[]/t[] indices compile-time (rule #20)
    for (int p = 0; p < 16; ++p) {
      const float px = pc[3*p+0], py = pc[3*p+1], pz = pc[3*p+2];
      float t[16];
#pragma unroll
      for (int i = 0; i < 16; ++i) t[i] = fmaf(nqx[i], px, qc[i]);
#pragma unroll
      for (int i = 0; i < 16; ++i) t[i] = fmaf(nqy[i], py, t[i]);
#pragma unroll
      for (int i = 0; i < 16; ++i) t[i] = fmaf(nqz[i], pz, t[i]);
      float m0 = fminf(fminf(t[0],  t[1]),  t[2]);
      float m1 = fminf(fminf(t[3],  t[4]),  t[5]);
      float m2 = fminf(fminf(t[6],  t[7]),  t[8]);
      float m3 = fminf(fminf(t[9],  t[10]), t[11]);
      float m4 = fminf(fminf(t[12], t[13]), t[14]);
      float r0 = fminf(fminf(m0, m1), m2);
      float r1 = fminf(fminf(m3, m4), t[15]);
      red[p][tid] = fminf(r0, r1);
    }
    __syncthreads();

    {
      const int p   = tid >> 4;
      const int sub = tid & 15;
      const float4* r4 = (const float4*)&red[p][sub * 16];
      float4 v0 = r4[0], v1 = r4[1], v2 = r4[2], v3 = r4[3];
      float w0 = fminf(fminf(v0.x, v0.y), fminf(v0.z, v0.w));
      float w1 = fminf(fminf(v1.x, v1.y), fminf(v1.z, v1.w));
      float w2 = fminf(fminf(v2.x, v2.y), fminf(v2.z, v2.w));
      float w3 = fminf(fminf(v3.x, v3.y), fminf(v3.z, v3.w));
      float v  = fminf(fminf(w0, w1), fminf(w2, w3));
#pragma unroll
      for (int o = 1; o < 16; o <<= 1) v = fminf(v, __shfl_xor(v, o));
      if (sub == 0) {
        int i = cbase + p;
        float px = pos[3*i+0], py = pos[3*i+1], pz = pos[3*i+2];
        float p2 = px*px + py*py + pz*pz;
        float d2 = fmaf(2.f, v, p2);
        d2 = fmaxf(d2, 1e-12f);
        int n = i & (N_SZ - 1);
        int b = i >> 10;
        xT[n * 64 + b] = sqrtf(d2);
      }
    }
    __syncthreads();
  }
}

// ---------------------------------------------------------------------------
// Kernel 2 (v3): K-split partial GEMM with global_load_lds W staging.
//   P[s][j][b] = sum_{k in slice} xT[k][b] * W[k][j]
// Block = 256 thr (4 waves), output tile 64(j) x 64(b). x chunk in LDS.
// W streamed through a 2-buffer LDS ring in super-steps of 16 k-rows:
//   - wave w DMAs rows w*4..w*4+3 with ONE global_load_lds_dwordx4
//     (per-lane global src: lane L -> row w*4+(L>>4), col (L&15)*4;
//      LDS dest linear: base + L*16)
//   - compute phase: 16 x (ds_read_b128 W row [2-way bank, free] +
//     ds_read_b128 x [broadcast] + 16 FMA)  ~= 512 wave-cycles
//   - vmcnt(0) + barrier (stage was issued BEFORE compute -> latency hidden)
// No VGPR pipeline buffers -> ~50 VGPR, no spill possible.
// ---------------------------------------------------------------------------
template <int J, int KSPAN>
__global__ __launch_bounds__(256, 2) void gemm3_kernel(
    const float* __restrict__ xT,   // [K][64]
    const float* __restrict__ W,    // [K][J]
    float* __restrict__ P)          // [ks][J][64]
{
  constexpr int NS = KSPAN / 16;     // super-steps of 16 k-rows
  const int jt   = blockIdx.x;
  const int s    = blockIdx.y;
  const int tid  = threadIdx.x;
  const int lane = tid & 63;
  const int wave = tid >> 6;
  const int jl = lane & 15;
  const int bq = lane >> 4;
  const int j0 = jt * 64 + jl * 4;
  const int b0 = wave * 16 + bq * 4;

  __shared__ __align__(16) float xs[KSPAN][64];
  __shared__ __align__(16) float wring[2][16][64];   // 2 x 4KB ring

  // per-lane global source for W staging (this wave's 4 rows of each 16-batch)
  const float* wsrc = W + ((size_t)s * KSPAN + wave * 4 + (lane >> 4)) * J
                        + jt * 64 + (lane & 15) * 4;

  // stage x chunk (coalesced float4 copy)
  {
    const float4* src4 = (const float4*)(xT + (size_t)s * KSPAN * 64);
    float4* dst4 = (float4*)&xs[0][0];
    constexpr int NITER = KSPAN / 16;   // KSPAN*64*4 / (256*16)
#pragma unroll
    for (int i = 0; i < NITER; ++i)
      dst4[i * 256 + tid] = src4[i * 256 + tid];
  }
  // prologue: stage super-step 0 into buf 0
  __builtin_amdgcn_global_load_lds(
      (const AS1 void*)wsrc,
      (AS3 void*)&wring[0][wave * 4][0], 16, 0, 0);
  asm volatile("s_waitcnt vmcnt(0)" ::: "memory");
  __syncthreads();

  float acc[4][4];
#pragma unroll
  for (int a = 0; a < 4; ++a)
#pragma unroll
    for (int c = 0; c < 4; ++c) acc[a][c] = 0.f;

#pragma unroll 1
  for (int t = 0; t < NS; ++t) {
    const int buf = t & 1;
    // issue next super-step's DMA first (hides under compute)
    if (t + 1 < NS) {
      __builtin_amdgcn_global_load_lds(
          (const AS1 void*)(wsrc + (size_t)(t + 1) * 16 * J),
          (AS3 void*)&wring[buf ^ 1][wave * 4][0], 16, 0, 0);
    }
    // compute 16 k-rows from current buffer
#pragma unroll
    for (int r = 0; r < 16; ++r) {
      float4 w4 = *(const float4*)&wring[buf][r][jl * 4];
      float4 x4 = *(const float4*)&xs[t * 16 + r][b0];
      const float wv[4] = {w4.x, w4.y, w4.z, w4.w};
      const float xv[4] = {x4.x, x4.y, x4.z, x4.w};
#pragma unroll
      for (int a = 0; a < 4; ++a)
#pragma unroll
        for (int c = 0; c < 4; ++c)
          acc[a][c] = fmaf(xv[a], wv[c], acc[a][c]);
    }
    // drain own DMA, then block-wide sync (protects ring reuse + x/W reads)
    asm volatile("s_waitcnt vmcnt(0)" ::: "memory");
    __syncthreads();
  }

#pragma unroll
  for (int c = 0; c < 4; ++c) {
    float4 o = make_float4(acc[0][c], acc[1][c], acc[2][c], acc[3][c]);
    *(float4*)(P + ((size_t)s * J + (j0 + c)) * 64 + b0) = o;
  }
}

// ---------------------------------------------------------------------------
// Kernel 3: reduce K-split partials + bias (+ReLU); optional transposed write.
// ---------------------------------------------------------------------------
template <int J, int KS, bool RELU, bool TRANS>
__global__ __launch_bounds__(256) void reduce_bias_kernel(
    const float* __restrict__ P,     // [KS][J][64]
    const float* __restrict__ bias,  // [J]
    float* __restrict__ out)         // TRANS ? [J][64] : [B][J]
{
  const int t = blockIdx.x * 256 + threadIdx.x;
  const int b = t & 63;
  const int j = t >> 6;
  float v = 0.f;
#pragma unroll
  for (int s = 0; s < KS; ++s) v += P[((size_t)s * J + j) * 64 + b];
  v += bias[j];
  if (RELU) v = fmaxf(v, 0.f);
  if (TRANS) out[j * 64 + b] = v;
  else       out[(size_t)b * J + j] = v;
}

// ---------------------------------------------------------------------------
extern "C" void kernel_launch(void* const* d_in, const int* in_sizes, int n_in,
                              void* d_out, int out_size, void* d_ws, size_t ws_size,
                              hipStream_t stream) {
  const float* pos   = (const float*)d_in[0];
  const float* basis = (const float*)d_in[1];
  const float* W0    = (const float*)d_in[2];
  const float* b0    = (const float*)d_in[3];
  const float* W1    = (const float*)d_in[4];
  const float* b1    = (const float*)d_in[5];
  const float* W2    = (const float*)d_in[6];
  const float* b2    = (const float*)d_in[7];
  const float* W3    = (const float*)d_in[8];
  const float* b3    = (const float*)d_in[9];
  float* out = (float*)d_out;

  char* ws = (char*)d_ws;
  float* P  = (float*)ws;                                  // 8 MiB partials
  float* xA = (float*)(ws + (8u << 20));                   // 512 KiB
  float* xB = (float*)(ws + (8u << 20) + (512u << 10));    // 512 KiB

  // 1) distances + min -> xT0 [1024][64] in xA
  dist_min_kernel<<<512, 256, 0, stream>>>(pos, basis, xA);

  // 2) layer 0: [64,1024] @ [1024,2048]; KSPAN=64 -> 16 slices, 512 blocks
  gemm3_kernel<HID_SZ, 64>
      <<<dim3(HID_SZ / 64, 1024 / 64), 256, 0, stream>>>(xA, W0, P);
  reduce_bias_kernel<HID_SZ, 16, true, true>
      <<<HID_SZ * 64 / 256, 256, 0, stream>>>(P, b0, xB);

  // 3) layer 1: [64,2048] @ [2048,2048]; KSPAN=128 -> 16 slices, 512 blocks
  gemm3_kernel<HID_SZ, 128>
      <<<dim3(HID_SZ / 64, 2048 / 128), 256, 0, stream>>>(xB, W1, P);
  reduce_bias_kernel<HID_SZ, 16, true, true>
      <<<HID_SZ * 64 / 256, 256, 0, stream>>>(P, b1, xA);

  // 4) layer 2
  gemm3_kernel<HID_SZ, 128>
      <<<dim3(HID_SZ / 64, 2048 / 128), 256, 0, stream>>>(xA, W2, P);
  reduce_bias_kernel<HID_SZ, 16, true, true>
      <<<HID_SZ * 64 / 256, 256, 0, stream>>>(P, b2, xB);

  // 5) layer 3: [64,2048] @ [2048,512]; KSPAN=32 -> 64 slices, 512 blocks
  gemm3_kernel<OUT_SZ, 32>
      <<<dim3(OUT_SZ / 64, 2048 / 32), 256, 0, stream>>>(xB, W3, P);
  reduce_bias_kernel<OUT_SZ, 64, false, false>
      <<<OUT_SZ * 64 / 256, 256, 0, stream>>>(P, b3, out);
}